// Round 3
// baseline (1636.511 us; speedup 1.0000x reference)
//
#include <hip/hip_runtime.h>

#define DM     1024
#define DI     2048
#define DST    16
#define NBATCH 4
#define SEQ    2048
#define MROWS  (NBATCH*SEQ)
#define NCHUNK 32
#define CLEN   (SEQ/NCHUNK)   // 64

typedef unsigned short u16;
typedef unsigned int   u32;
typedef unsigned long long u64;

typedef __bf16 bf16x8 __attribute__((ext_vector_type(8)));
typedef float  f32x4  __attribute__((ext_vector_type(4)));

typedef const __attribute__((address_space(1))) u32* gas_ptr;
typedef __attribute__((address_space(3))) u32* las_ptr;
#define GLOAD16(g, l) __builtin_amdgcn_global_load_lds((gas_ptr)(g), (las_ptr)(l), 16, 0, 0)

static __device__ __forceinline__ u16 f2bf(float f) {
  u32 u = __builtin_bit_cast(u32, f);
  u = (u + 0x7FFFu + ((u >> 16) & 1u)) >> 16;   // RNE, finite only
  return (u16)u;
}
static __device__ __forceinline__ float bf2f(u16 h) {
  return __builtin_bit_cast(float, (u32)h << 16);
}
static __device__ __forceinline__ float sigmoid_f(float x) {
  return __builtin_amdgcn_rcpf(1.f + __expf(-x));
}

// ------------------------------------------------- split cast: f32 -> (hi, lo) bf16
__global__ __launch_bounds__(256)
void split_cast_k(const float* __restrict__ in, u16* __restrict__ hi,
                  u16* __restrict__ lo, int n4) {
  const int i = blockIdx.x * 256 + threadIdx.x;
  if (i >= n4) return;
  const float4 v = reinterpret_cast<const float4*>(in)[i];
  u16 h0 = f2bf(v.x), h1 = f2bf(v.y), h2 = f2bf(v.z), h3 = f2bf(v.w);
  u16 l0 = f2bf(v.x - bf2f(h0)), l1 = f2bf(v.y - bf2f(h1));
  u16 l2 = f2bf(v.z - bf2f(h2)), l3 = f2bf(v.w - bf2f(h3));
  reinterpret_cast<u64*>(hi)[i] = (u64)h0 | ((u64)h1<<16) | ((u64)h2<<32) | ((u64)h3<<48);
  reinterpret_cast<u64*>(lo)[i] = (u64)l0 | ((u64)l1<<16) | ((u64)l2<<32) | ((u64)l3<<48);
}

// ------------------------------------------------- transpose casts
// in: R x C f32 -> out: C x R bf16 (hi/lo pair, lo may be null)
template<int SPLIT>
__global__ __launch_bounds__(256)
void transpose_cast_k(const float* __restrict__ in, u16* __restrict__ hi,
                      u16* __restrict__ lo, int R, int C) {
  __shared__ float tile[32][33];
  const int c0 = blockIdx.x * 32, r0 = blockIdx.y * 32;
  const int tx = threadIdx.x, ty = threadIdx.y;
  #pragma unroll
  for (int i = ty; i < 32; i += 8)
    tile[i][tx] = in[(size_t)(r0 + i) * C + c0 + tx];
  __syncthreads();
  #pragma unroll
  for (int i = ty; i < 32; i += 8) {
    const float v = tile[tx][i];
    const u16 h = f2bf(v);
    hi[(size_t)(c0 + i) * R + r0 + tx] = h;
    if (SPLIT) lo[(size_t)(c0 + i) * R + r0 + tx] = f2bf(v - bf2f(h));
  }
}

// ------------------------------------------------- split-bf16 MFMA GEMM (~f32 fidelity)
// A = Ah+Al (M x K), Bt = Bh+Bl (N x K, transposed). acc += Ah*Bh + Ah*Bl + Al*Bh.
// EPI 0: f32 store, 1: bf16 store, 2: softplus(acc+bias) f32 store.
template<int EPI>
__global__ __launch_bounds__(256)
void gemm_split_k(const u16* __restrict__ Ah, const u16* __restrict__ Al,
                  const u16* __restrict__ Bh, const u16* __restrict__ Bl,
                  void* __restrict__ Cout, const float* __restrict__ bias,
                  int N, int K) {
  __shared__ __align__(16) u16 Ash[128*64];
  __shared__ __align__(16) u16 Asl[128*64];
  __shared__ __align__(16) u16 Bsh[128*64];
  __shared__ __align__(16) u16 Bsl[128*64];
  const int tid  = threadIdx.x;
  const int lane = tid & 63;
  const int wave = tid >> 6;
  const int wm = wave >> 1, wn = wave & 1;
  const int bm = blockIdx.x * 128, bn = blockIdx.y * 128;

  const int srow = lane >> 3;
  const int scol = (lane & 7) * 8;
  const size_t abase = (size_t)(bm + srow) * K + scol;
  const size_t bbase = (size_t)(bn + srow) * K + scol;

  f32x4 acc[4][4];
  #pragma unroll
  for (int i = 0; i < 4; ++i)
    #pragma unroll
    for (int j = 0; j < 4; ++j)
      #pragma unroll
      for (int r = 0; r < 4; ++r) acc[i][j][r] = 0.f;

  for (int k0 = 0; k0 < K; k0 += 64) {
    #pragma unroll
    for (int i = 0; i < 4; ++i) {
      const int ci = wave * 4 + i;
      const size_t ao = abase + (size_t)(ci * 8) * K + k0;
      const size_t bo = bbase + (size_t)(ci * 8) * K + k0;
      GLOAD16(Ah + ao, Ash + ci * 512);
      GLOAD16(Al + ao, Asl + ci * 512);
      GLOAD16(Bh + bo, Bsh + ci * 512);
      GLOAD16(Bl + bo, Bsl + ci * 512);
    }
    __syncthreads();
    #pragma unroll
    for (int kk = 0; kk < 2; ++kk) {
      const int kof = kk * 32 + (lane >> 4) * 8;
      bf16x8 afh[4], afl[4], bfh[4], bfl[4];
      #pragma unroll
      for (int i = 0; i < 4; ++i) {
        const int ro = (wm*64 + i*16 + (lane & 15)) * 64 + kof;
        afh[i] = *reinterpret_cast<const bf16x8*>(&Ash[ro]);
        afl[i] = *reinterpret_cast<const bf16x8*>(&Asl[ro]);
      }
      #pragma unroll
      for (int j = 0; j < 4; ++j) {
        const int ro = (wn*64 + j*16 + (lane & 15)) * 64 + kof;
        bfh[j] = *reinterpret_cast<const bf16x8*>(&Bsh[ro]);
        bfl[j] = *reinterpret_cast<const bf16x8*>(&Bsl[ro]);
      }
      #pragma unroll
      for (int i = 0; i < 4; ++i)
        #pragma unroll
        for (int j = 0; j < 4; ++j) {
          acc[i][j] = __builtin_amdgcn_mfma_f32_16x16x32_bf16(afh[i], bfh[j], acc[i][j], 0, 0, 0);
          acc[i][j] = __builtin_amdgcn_mfma_f32_16x16x32_bf16(afh[i], bfl[j], acc[i][j], 0, 0, 0);
          acc[i][j] = __builtin_amdgcn_mfma_f32_16x16x32_bf16(afl[i], bfh[j], acc[i][j], 0, 0, 0);
        }
    }
    __syncthreads();
  }

  const int r0 = (lane >> 4) * 4;
  const int cc = lane & 15;
  #pragma unroll
  for (int i = 0; i < 4; ++i) {
    #pragma unroll
    for (int j = 0; j < 4; ++j) {
      const int gr = bm + wm*64 + i*16 + r0;
      const int gc = bn + wn*64 + j*16 + cc;
      #pragma unroll
      for (int r = 0; r < 4; ++r) {
        float v = acc[i][j][r];
        const size_t off = (size_t)(gr + r) * N + gc;
        if (EPI == 0) {
          ((float*)Cout)[off] = v;
        } else if (EPI == 1) {
          ((u16*)Cout)[off] = f2bf(v);
        } else {
          v += bias[gc];
          v = (v > 20.f) ? v : __logf(1.f + __expf(v));
          ((float*)Cout)[off] = v;
        }
      }
    }
  }
}

// ------------------------------------------------- plain bf16 GEMM (final projection)
__global__ __launch_bounds__(256)
void gemm_bf16_k(const u16* __restrict__ A, const u16* __restrict__ Bt,
                 float* __restrict__ Cout, int N, int K) {
  __shared__ __align__(16) u16 As[128*64];
  __shared__ __align__(16) u16 Bs[128*64];
  const int tid  = threadIdx.x;
  const int lane = tid & 63;
  const int wave = tid >> 6;
  const int wm = wave >> 1, wn = wave & 1;
  const int bm = blockIdx.x * 128, bn = blockIdx.y * 128;
  const int srow = lane >> 3;
  const int scol = (lane & 7) * 8;
  const u16* Ag = A  + (size_t)(bm + srow) * K + scol;
  const u16* Bg = Bt + (size_t)(bn + srow) * K + scol;
  f32x4 acc[4][4];
  #pragma unroll
  for (int i = 0; i < 4; ++i)
    #pragma unroll
    for (int j = 0; j < 4; ++j)
      #pragma unroll
      for (int r = 0; r < 4; ++r) acc[i][j][r] = 0.f;
  for (int k0 = 0; k0 < K; k0 += 64) {
    #pragma unroll
    for (int i = 0; i < 4; ++i) {
      const int ci = wave * 4 + i;
      GLOAD16(Ag + (size_t)(ci * 8) * K + k0, As + ci * 512);
      GLOAD16(Bg + (size_t)(ci * 8) * K + k0, Bs + ci * 512);
    }
    __syncthreads();
    #pragma unroll
    for (int kk = 0; kk < 2; ++kk) {
      const int kof = kk * 32 + (lane >> 4) * 8;
      bf16x8 af[4], bfv[4];
      #pragma unroll
      for (int i = 0; i < 4; ++i)
        af[i] = *reinterpret_cast<const bf16x8*>(&As[(wm*64 + i*16 + (lane & 15)) * 64 + kof]);
      #pragma unroll
      for (int j = 0; j < 4; ++j)
        bfv[j] = *reinterpret_cast<const bf16x8*>(&Bs[(wn*64 + j*16 + (lane & 15)) * 64 + kof]);
      #pragma unroll
      for (int i = 0; i < 4; ++i)
        #pragma unroll
        for (int j = 0; j < 4; ++j)
          acc[i][j] = __builtin_amdgcn_mfma_f32_16x16x32_bf16(af[i], bfv[j], acc[i][j], 0, 0, 0);
    }
    __syncthreads();
  }
  const int r0 = (lane >> 4) * 4;
  const int cc = lane & 15;
  #pragma unroll
  for (int i = 0; i < 4; ++i)
    #pragma unroll
    for (int j = 0; j < 4; ++j) {
      const int gr = bm + wm*64 + i*16 + r0;
      const int gc = bn + wn*64 + j*16 + cc;
      #pragma unroll
      for (int r = 0; r < 4; ++r)
        Cout[(size_t)(gr + r) * N + gc] = acc[i][j][r];
    }
}

// ------------------------------------------------- conv1d + silu (f32 in, hi/lo out), per batch
__global__ __launch_bounds__(256)
void conv_silu_k(const float* __restrict__ xin, const float* __restrict__ cw,
                 const float* __restrict__ cb, u16* __restrict__ xh,
                 u16* __restrict__ xl) {
  const int idx = blockIdx.x * 256 + threadIdx.x;   // l*DI + d
  const int d = idx & (DI - 1);
  const int l = idx >> 11;
  float acc = cb[d];
  #pragma unroll
  for (int i = 0; i < 4; ++i) {
    const int ls = l + i - 3;
    if (ls >= 0)
      acc = fmaf(xin[(size_t)ls * DI + d], cw[d*4 + i], acc);
  }
  const float s = acc * sigmoid_f(acc);
  const u16 h = f2bf(s);
  xh[idx] = h;
  xl[idx] = f2bf(s - bf2f(h));
}

// ------------------------------------------------- x_conv @ W_x  (M=SEQ, K=DI, N=32), per batch
__global__ __launch_bounds__(256)
void gemm_bc_k(const u16* __restrict__ Xh, const u16* __restrict__ Xl,
               const float* __restrict__ Wx, float* __restrict__ BC) {
  __shared__ float As[32][33];
  __shared__ float Bsh[32][33];
  const int tid = threadIdx.x;
  const int m0 = blockIdx.x * 32;
  const int tm = tid >> 3;
  const int n4 = (tid & 7) * 4;
  const int sr = tid >> 3, sc = (tid & 7) * 4;
  float acc[4] = {0.f, 0.f, 0.f, 0.f};
  for (int k0 = 0; k0 < DI; k0 += 32) {
    const size_t go = (size_t)(m0 + sr) * DI + k0 + sc;
    const u64 ph = *reinterpret_cast<const u64*>(&Xh[go]);
    const u64 pl = *reinterpret_cast<const u64*>(&Xl[go]);
    As[sr][sc]   = bf2f((u16)ph)       + bf2f((u16)pl);
    As[sr][sc+1] = bf2f((u16)(ph>>16)) + bf2f((u16)(pl>>16));
    As[sr][sc+2] = bf2f((u16)(ph>>32)) + bf2f((u16)(pl>>32));
    As[sr][sc+3] = bf2f((u16)(ph>>48)) + bf2f((u16)(pl>>48));
    const float4 vb = *reinterpret_cast<const float4*>(&Wx[(size_t)(k0 + sr) * 32 + sc]);
    Bsh[sr][sc] = vb.x; Bsh[sr][sc+1] = vb.y; Bsh[sr][sc+2] = vb.z; Bsh[sr][sc+3] = vb.w;
    __syncthreads();
    #pragma unroll
    for (int k = 0; k < 32; ++k) {
      const float a = As[tm][k];
      #pragma unroll
      for (int j = 0; j < 4; ++j) acc[j] = fmaf(a, Bsh[k][n4 + j], acc[j]);
    }
    __syncthreads();
  }
  #pragma unroll
  for (int j = 0; j < 4; ++j) BC[(size_t)(m0 + tm) * 32 + n4 + j] = acc[j];
}

// ------------------------------------------------- selective scan (per batch, 3-pass chunked)
__global__ __launch_bounds__(256)
void scan1_k(const float* __restrict__ dt, const u16* __restrict__ uh,
             const u16* __restrict__ ul, const float* __restrict__ BC,
             const float* __restrict__ A_log, float* __restrict__ Pb,
             float* __restrict__ Sb) {
  const int blk = blockIdx.x;              // c*8 + db
  const int db = blk & 7;
  const int c  = blk >> 3;
  const int d  = db * 256 + threadIdx.x;
  float Av[DST];
  #pragma unroll
  for (int n = 0; n < DST; ++n) Av[n] = -__expf(A_log[n]);
  float P[DST], S[DST];
  #pragma unroll
  for (int n = 0; n < DST; ++n) { P[n] = 1.f; S[n] = 0.f; }
  for (int s = 0; s < CLEN; ++s) {
    const size_t row = (size_t)(c * CLEN + s);
    const float dtv = dt[row * DI + d];
    const float uv  = bf2f(uh[row * DI + d]) + bf2f(ul[row * DI + d]);
    const float dtu = dtv * uv;
    const float* Brow = &BC[row * 32];
    #pragma unroll
    for (int n = 0; n < DST; ++n) {
      const float a = __expf(dtv * Av[n]);
      P[n] *= a;
      S[n] = fmaf(a, S[n], dtu * Brow[n]);
    }
  }
  const size_t off = ((size_t)c * DI + d) * DST;
  #pragma unroll
  for (int n = 0; n < DST; ++n) { Pb[off + n] = P[n]; Sb[off + n] = S[n]; }
}

__global__ __launch_bounds__(256)
void scan2_k(const float* __restrict__ Pb, const float* __restrict__ Sb,
             float* __restrict__ hs) {
  const int idx = blockIdx.x * 256 + threadIdx.x;   // d*16 + n, over DI*DST
  const int n = idx & (DST - 1);
  const int d = idx >> 4;
  float h = 0.f;
  #pragma unroll
  for (int c = 0; c < NCHUNK; ++c) {
    const size_t off = ((size_t)c * DI + d) * DST + n;
    hs[off] = h;
    h = fmaf(Pb[off], h, Sb[off]);
  }
}

__global__ __launch_bounds__(256)
void scan3_k(const float* __restrict__ dt, const u16* __restrict__ uh,
             const u16* __restrict__ ul, const float* __restrict__ BC,
             const float* __restrict__ A_log, const float* __restrict__ hs,
             float* __restrict__ y) {
  const int blk = blockIdx.x;
  const int db = blk & 7;
  const int c  = blk >> 3;
  const int d  = db * 256 + threadIdx.x;
  float Av[DST];
  #pragma unroll
  for (int n = 0; n < DST; ++n) Av[n] = -__expf(A_log[n]);
  float h[DST];
  const size_t hoff = ((size_t)c * DI + d) * DST;
  #pragma unroll
  for (int n = 0; n < DST; ++n) h[n] = hs[hoff + n];
  for (int s = 0; s < CLEN; ++s) {
    const size_t row = (size_t)(c * CLEN + s);
    const float dtv = dt[row * DI + d];
    const float uv  = bf2f(uh[row * DI + d]) + bf2f(ul[row * DI + d]);
    const float dtu = dtv * uv;
    const float* Brow = &BC[row * 32];
    float yv = 0.f;
    #pragma unroll
    for (int n = 0; n < DST; ++n) {
      const float a = __expf(dtv * Av[n]);
      h[n] = fmaf(a, h[n], dtu * Brow[n]);
      yv = fmaf(h[n], Brow[DST + n], yv);
    }
    y[row * DI + d] = yv;
  }
}

// ------------------------------------------------- gate: g = (y + xc*D)*silu(z) -> bf16 (in z)
__global__ __launch_bounds__(256)
void elemwise_k(const float* __restrict__ y, const u16* __restrict__ xh,
                const u16* __restrict__ xl, const float* __restrict__ Dv,
                u16* __restrict__ z) {
  const int idx = blockIdx.x * 256 + threadIdx.x;
  const int d = idx & (DI - 1);
  const float zf = bf2f(z[idx]);
  const float xc = bf2f(xh[idx]) + bf2f(xl[idx]);
  float v = fmaf(xc, Dv[d], y[idx]);
  v *= zf * sigmoid_f(zf);
  z[idx] = f2bf(v);
}

// ================================================================ launch
extern "C" void kernel_launch(void* const* d_in, const int* in_sizes, int n_in,
                              void* d_out, int out_size, void* d_ws, size_t ws_size,
                              hipStream_t stream) {
  (void)in_sizes; (void)n_in;
  const float* x      = (const float*)d_in[0];
  const float* W_in   = (const float*)d_in[1];
  const float* conv_w = (const float*)d_in[2];
  const float* conv_b = (const float*)d_in[3];
  const float* W_x    = (const float*)d_in[4];
  const float* W_dt   = (const float*)d_in[5];
  const float* b_dt   = (const float*)d_in[6];
  const float* A_log  = (const float*)d_in[7];
  const float* Dvec   = (const float*)d_in[8];
  const float* W_out  = (const float*)d_in[9];
  float* out = (float*)d_out;

  // ---- workspace (~160 MB; no aliasing) ----
  char* w = (char*)d_ws;
  size_t used = 0;
  auto alloc = [&](size_t bytes) {
    char* p = w + used; used += (bytes + 255) & ~(size_t)255; return p;
  };
  u16*   x_h   = (u16*)alloc((size_t)MROWS * DM * 2);        // full x split
  u16*   x_l   = (u16*)alloc((size_t)MROWS * DM * 2);
  u16*   WinT_h = (u16*)alloc((size_t)(2*DI) * DM * 2);
  u16*   WinT_l = (u16*)alloc((size_t)(2*DI) * DM * 2);
  u16*   WdtT_h = (u16*)alloc((size_t)DI * DI * 2);
  u16*   WdtT_l = (u16*)alloc((size_t)DI * DI * 2);
  u16*   WoutT  = (u16*)alloc((size_t)DM * DI * 2);
  // per-batch activation buffers (reused across the 4 batch passes)
  float* xin  = (float*)alloc((size_t)SEQ * DI * 4);
  u16*   z_bf = (u16*)  alloc((size_t)SEQ * DI * 2);
  u16*   xc_h = (u16*)  alloc((size_t)SEQ * DI * 2);
  u16*   xc_l = (u16*)  alloc((size_t)SEQ * DI * 2);
  float* dtb  = (float*)alloc((size_t)SEQ * DI * 4);
  float* BC   = (float*)alloc((size_t)SEQ * 32 * 4);
  float* Pb   = (float*)alloc((size_t)NCHUNK * DI * DST * 4);
  float* Sb   = (float*)alloc((size_t)NCHUNK * DI * DST * 4);
  float* hsb  = (float*)alloc((size_t)NCHUNK * DI * DST * 4);
  float* ybuf = (float*)alloc((size_t)SEQ * DI * 4);
  const size_t NEED = used;

  if (ws_size < NEED) {   // diagnostic fallback: clean absmax failure, not a crash
    hipMemsetAsync(d_out, 0, (size_t)out_size * 4, stream);
    return;
  }

  // weight prep (once)
  split_cast_k<<<(MROWS*DM/4 + 255)/256, 256, 0, stream>>>(x, x_h, x_l, MROWS*DM/4);
  transpose_cast_k<1><<<dim3((2*DI)/32, DM/32), dim3(32,8), 0, stream>>>(W_in, WinT_h, WinT_l, DM, 2*DI);
  transpose_cast_k<1><<<dim3(DI/32, DI/32), dim3(32,8), 0, stream>>>(W_dt, WdtT_h, WdtT_l, DI, DI);
  transpose_cast_k<0><<<dim3(DM/32, DI/32), dim3(32,8), 0, stream>>>(W_out, WoutT, nullptr, DI, DM);

  for (int b = 0; b < NBATCH; ++b) {
    const u16* xbh = x_h + (size_t)b * SEQ * DM;
    const u16* xbl = x_l + (size_t)b * SEQ * DM;

    // x_in = x @ W_in[:, :DI]  (f32)
    gemm_split_k<0><<<dim3(SEQ/128, DI/128), 256, 0, stream>>>(
        xbh, xbl, WinT_h, WinT_l, xin, nullptr, DI, DM);
    // z = x @ W_in[:, DI:]  (bf16)
    gemm_split_k<1><<<dim3(SEQ/128, DI/128), 256, 0, stream>>>(
        xbh, xbl, WinT_h + (size_t)DI*DM, WinT_l + (size_t)DI*DM, z_bf, nullptr, DI, DM);

    // causal depthwise conv + silu -> xc hi/lo
    conv_silu_k<<<SEQ*DI/256, 256, 0, stream>>>(xin, conv_w, conv_b, xc_h, xc_l);

    // B,C = x_conv @ W_x
    gemm_bc_k<<<SEQ/32, 256, 0, stream>>>(xc_h, xc_l, W_x, BC);

    // dt = softplus(x_conv @ W_dt + b_dt)  (f32)
    gemm_split_k<2><<<dim3(SEQ/128, DI/128), 256, 0, stream>>>(
        xc_h, xc_l, WdtT_h, WdtT_l, dtb, b_dt, DI, DI);

    // selective scan (chunked linear recurrence), y f32
    scan1_k<<<NCHUNK*(DI/256), 256, 0, stream>>>(dtb, xc_h, xc_l, BC, A_log, Pb, Sb);
    scan2_k<<<DI*DST/256,      256, 0, stream>>>(Pb, Sb, hsb);
    scan3_k<<<NCHUNK*(DI/256), 256, 0, stream>>>(dtb, xc_h, xc_l, BC, A_log, hsb, ybuf);

    // gate + skip (bf16, in place into z)
    elemwise_k<<<SEQ*DI/256, 256, 0, stream>>>(ybuf, xc_h, xc_l, Dvec, z_bf);

    // out = gated @ W_out
    gemm_bf16_k<<<dim3(SEQ/128, DM/128), 256, 0, stream>>>(
        z_bf, WoutT, out + (size_t)b * SEQ * DM, DM, DI);
  }
}

// Round 4
// 1093.648 us; speedup vs baseline: 1.4964x; 1.4964x over previous
//
#include <hip/hip_runtime.h>

#define DM     1024
#define DI     2048
#define DST    16
#define NBATCH 4
#define SEQ    2048
#define MROWS  (NBATCH*SEQ)
#define PROWS  (2*SEQ)        // rows per batch-pair iteration (4096)
#define NCHUNK 16
#define CLEN   (SEQ/NCHUNK)   // 128
#define NCAT   (DI + 128)     // 2176: dt GEMM N with W_x folded in

typedef unsigned short u16;
typedef unsigned int   u32;
typedef unsigned long long u64;

typedef __bf16 bf16x8 __attribute__((ext_vector_type(8)));
typedef float  f32x4  __attribute__((ext_vector_type(4)));

typedef const __attribute__((address_space(1))) u32* gas_ptr;
typedef __attribute__((address_space(3))) u32* las_ptr;
#define GLOAD16(g, l) __builtin_amdgcn_global_load_lds((gas_ptr)(g), (las_ptr)(l), 16, 0, 0)

static __device__ __forceinline__ u16 f2bf(float f) {
  u32 u = __builtin_bit_cast(u32, f);
  u = (u + 0x7FFFu + ((u >> 16) & 1u)) >> 16;   // RNE, finite only
  return (u16)u;
}
static __device__ __forceinline__ float bf2f(u16 h) {
  return __builtin_bit_cast(float, (u32)h << 16);
}
static __device__ __forceinline__ float sigmoid_f(float x) {
  return __builtin_amdgcn_rcpf(1.f + __expf(-x));
}

// ------------------------------------------------- split cast: f32 -> (hi, lo) bf16
__global__ __launch_bounds__(256)
void split_cast_k(const float* __restrict__ in, u16* __restrict__ hi,
                  u16* __restrict__ lo, int n4) {
  const int i = blockIdx.x * 256 + threadIdx.x;
  if (i >= n4) return;
  const float4 v = reinterpret_cast<const float4*>(in)[i];
  u16 h0 = f2bf(v.x), h1 = f2bf(v.y), h2 = f2bf(v.z), h3 = f2bf(v.w);
  u16 l0 = f2bf(v.x - bf2f(h0)), l1 = f2bf(v.y - bf2f(h1));
  u16 l2 = f2bf(v.z - bf2f(h2)), l3 = f2bf(v.w - bf2f(h3));
  reinterpret_cast<u64*>(hi)[i] = (u64)h0 | ((u64)h1<<16) | ((u64)h2<<32) | ((u64)h3<<48);
  reinterpret_cast<u64*>(lo)[i] = (u64)l0 | ((u64)l1<<16) | ((u64)l2<<32) | ((u64)l3<<48);
}

// ------------------------------------------------- transpose casts (R x C f32 -> C x R bf16 hi[/lo])
template<int SPLIT>
__global__ __launch_bounds__(256)
void transpose_cast_k(const float* __restrict__ in, u16* __restrict__ hi,
                      u16* __restrict__ lo, int R, int C) {
  __shared__ float tile[32][33];
  const int c0 = blockIdx.x * 32, r0 = blockIdx.y * 32;
  const int tx = threadIdx.x, ty = threadIdx.y;
  #pragma unroll
  for (int i = ty; i < 32; i += 8)
    tile[i][tx] = in[(size_t)(r0 + i) * C + c0 + tx];
  __syncthreads();
  #pragma unroll
  for (int i = ty; i < 32; i += 8) {
    const float v = tile[tx][i];
    const u16 h = f2bf(v);
    hi[(size_t)(c0 + i) * R + r0 + tx] = h;
    if (SPLIT) lo[(size_t)(c0 + i) * R + r0 + tx] = f2bf(v - bf2f(h));
  }
}

// fill rows [DI, NCAT) of WdtcatT: rows DI..DI+31 = W_x^T, rest zero.
__global__ __launch_bounds__(256)
void wcat_tail_k(const float* __restrict__ Wx, u16* __restrict__ hi,
                 u16* __restrict__ lo) {
  const int idx = blockIdx.x * 256 + threadIdx.x;   // over 128*2048
  const int k = idx & (DI - 1);
  const int rw = idx >> 11;                          // 0..127
  float v = (rw < 32) ? Wx[(size_t)k * 32 + rw] : 0.f;
  const u16 h = f2bf(v);
  hi[(size_t)(DI + rw) * DI + k] = h;
  lo[(size_t)(DI + rw) * DI + k] = f2bf(v - bf2f(h));
}

// ------------------------------------------------- split-bf16 MFMA GEMM (~f32 fidelity)
// A = Ah+Al (M x K), Bt = Bh+Bl (N x K). acc += Ah*Bh + Ah*Bl + Al*Bh.
// EPI 0: f32 store (stride N). EPI 3: dt/BC routing — gc<DI: softplus(v+bias[gc])
// -> dtb (stride DI); DI<=gc<DI+32: -> bc (stride 32); else discard.
template<int EPI>
__global__ __launch_bounds__(256)
void gemm_split_k(const u16* __restrict__ Ah, const u16* __restrict__ Al,
                  const u16* __restrict__ Bh, const u16* __restrict__ Bl,
                  float* __restrict__ Cout, const float* __restrict__ bias,
                  float* __restrict__ bc, int N, int K) {
  __shared__ __align__(16) u16 Ash[128*64];
  __shared__ __align__(16) u16 Asl[128*64];
  __shared__ __align__(16) u16 Bsh[128*64];
  __shared__ __align__(16) u16 Bsl[128*64];
  const int tid  = threadIdx.x;
  const int lane = tid & 63;
  const int wave = tid >> 6;
  const int wm = wave >> 1, wn = wave & 1;
  const int bm = blockIdx.x * 128, bn = blockIdx.y * 128;

  const int srow = lane >> 3;
  const int scol = (lane & 7) * 8;
  const size_t abase = (size_t)(bm + srow) * K + scol;
  const size_t bbase = (size_t)(bn + srow) * K + scol;

  f32x4 acc[4][4];
  #pragma unroll
  for (int i = 0; i < 4; ++i)
    #pragma unroll
    for (int j = 0; j < 4; ++j)
      #pragma unroll
      for (int r = 0; r < 4; ++r) acc[i][j][r] = 0.f;

  for (int k0 = 0; k0 < K; k0 += 64) {
    #pragma unroll
    for (int i = 0; i < 4; ++i) {
      const int ci = wave * 4 + i;
      const size_t ao = abase + (size_t)(ci * 8) * K + k0;
      const size_t bo = bbase + (size_t)(ci * 8) * K + k0;
      GLOAD16(Ah + ao, Ash + ci * 512);
      GLOAD16(Al + ao, Asl + ci * 512);
      GLOAD16(Bh + bo, Bsh + ci * 512);
      GLOAD16(Bl + bo, Bsl + ci * 512);
    }
    __syncthreads();
    #pragma unroll
    for (int kk = 0; kk < 2; ++kk) {
      const int kof = kk * 32 + (lane >> 4) * 8;
      bf16x8 afh[4], afl[4], bfh[4], bfl[4];
      #pragma unroll
      for (int i = 0; i < 4; ++i) {
        const int ro = (wm*64 + i*16 + (lane & 15)) * 64 + kof;
        afh[i] = *reinterpret_cast<const bf16x8*>(&Ash[ro]);
        afl[i] = *reinterpret_cast<const bf16x8*>(&Asl[ro]);
      }
      #pragma unroll
      for (int j = 0; j < 4; ++j) {
        const int ro = (wn*64 + j*16 + (lane & 15)) * 64 + kof;
        bfh[j] = *reinterpret_cast<const bf16x8*>(&Bsh[ro]);
        bfl[j] = *reinterpret_cast<const bf16x8*>(&Bsl[ro]);
      }
      #pragma unroll
      for (int i = 0; i < 4; ++i)
        #pragma unroll
        for (int j = 0; j < 4; ++j) {
          acc[i][j] = __builtin_amdgcn_mfma_f32_16x16x32_bf16(afh[i], bfh[j], acc[i][j], 0, 0, 0);
          acc[i][j] = __builtin_amdgcn_mfma_f32_16x16x32_bf16(afh[i], bfl[j], acc[i][j], 0, 0, 0);
          acc[i][j] = __builtin_amdgcn_mfma_f32_16x16x32_bf16(afl[i], bfh[j], acc[i][j], 0, 0, 0);
        }
    }
    __syncthreads();
  }

  const int r0 = (lane >> 4) * 4;
  const int cc = lane & 15;
  #pragma unroll
  for (int i = 0; i < 4; ++i) {
    #pragma unroll
    for (int j = 0; j < 4; ++j) {
      const int gr = bm + wm*64 + i*16 + r0;
      const int gc = bn + wn*64 + j*16 + cc;
      #pragma unroll
      for (int r = 0; r < 4; ++r) {
        float v = acc[i][j][r];
        if (EPI == 0) {
          Cout[(size_t)(gr + r) * N + gc] = v;
        } else {  // EPI == 3
          if (gc < DI) {
            v += bias[gc];
            v = (v > 20.f) ? v : __logf(1.f + __expf(v));
            Cout[(size_t)(gr + r) * DI + gc] = v;
          } else if (gc < DI + 32) {
            bc[(size_t)(gr + r) * 32 + (gc - DI)] = v;
          }
        }
      }
    }
  }
}

// ------------------------------------------------- plain bf16 GEMM. EPI 0: f32 out, 1: bf16 out.
template<int EPI>
__global__ __launch_bounds__(256)
void gemm_bf16_k(const u16* __restrict__ A, const u16* __restrict__ Bt,
                 void* __restrict__ Cout, int N, int K) {
  __shared__ __align__(16) u16 As[128*64];
  __shared__ __align__(16) u16 Bs[128*64];
  const int tid  = threadIdx.x;
  const int lane = tid & 63;
  const int wave = tid >> 6;
  const int wm = wave >> 1, wn = wave & 1;
  const int bm = blockIdx.x * 128, bn = blockIdx.y * 128;
  const int srow = lane >> 3;
  const int scol = (lane & 7) * 8;
  const u16* Ag = A  + (size_t)(bm + srow) * K + scol;
  const u16* Bg = Bt + (size_t)(bn + srow) * K + scol;
  f32x4 acc[4][4];
  #pragma unroll
  for (int i = 0; i < 4; ++i)
    #pragma unroll
    for (int j = 0; j < 4; ++j)
      #pragma unroll
      for (int r = 0; r < 4; ++r) acc[i][j][r] = 0.f;
  for (int k0 = 0; k0 < K; k0 += 64) {
    #pragma unroll
    for (int i = 0; i < 4; ++i) {
      const int ci = wave * 4 + i;
      GLOAD16(Ag + (size_t)(ci * 8) * K + k0, As + ci * 512);
      GLOAD16(Bg + (size_t)(ci * 8) * K + k0, Bs + ci * 512);
    }
    __syncthreads();
    #pragma unroll
    for (int kk = 0; kk < 2; ++kk) {
      const int kof = kk * 32 + (lane >> 4) * 8;
      bf16x8 af[4], bfv[4];
      #pragma unroll
      for (int i = 0; i < 4; ++i)
        af[i] = *reinterpret_cast<const bf16x8*>(&As[(wm*64 + i*16 + (lane & 15)) * 64 + kof]);
      #pragma unroll
      for (int j = 0; j < 4; ++j)
        bfv[j] = *reinterpret_cast<const bf16x8*>(&Bs[(wn*64 + j*16 + (lane & 15)) * 64 + kof]);
      #pragma unroll
      for (int i = 0; i < 4; ++i)
        #pragma unroll
        for (int j = 0; j < 4; ++j)
          acc[i][j] = __builtin_amdgcn_mfma_f32_16x16x32_bf16(af[i], bfv[j], acc[i][j], 0, 0, 0);
    }
    __syncthreads();
  }
  const int r0 = (lane >> 4) * 4;
  const int cc = lane & 15;
  #pragma unroll
  for (int i = 0; i < 4; ++i)
    #pragma unroll
    for (int j = 0; j < 4; ++j) {
      const int gr = bm + wm*64 + i*16 + r0;
      const int gc = bn + wn*64 + j*16 + cc;
      #pragma unroll
      for (int r = 0; r < 4; ++r) {
        if (EPI == 0) ((float*)Cout)[(size_t)(gr + r) * N + gc] = acc[i][j][r];
        else          ((u16*)Cout)[(size_t)(gr + r) * N + gc] = f2bf(acc[i][j][r]);
      }
    }
}

// ------------------------------------------------- conv1d + silu (f32 in, hi/lo out), per pair (2 batches)
__global__ __launch_bounds__(256)
void conv_silu_k(const float* __restrict__ xin, const float* __restrict__ cw,
                 const float* __restrict__ cb, u16* __restrict__ xh,
                 u16* __restrict__ xl) {
  const int idx = blockIdx.x * 256 + threadIdx.x;   // row*DI + d, row in [0,PROWS)
  const int d = idx & (DI - 1);
  const int row = idx >> 11;
  const int l = row & (SEQ - 1);
  const int bb = row >> 11;                          // local batch 0/1
  float acc = cb[d];
  #pragma unroll
  for (int i = 0; i < 4; ++i) {
    const int ls = l + i - 3;
    if (ls >= 0)
      acc = fmaf(xin[(size_t)(bb * SEQ + ls) * DI + d], cw[d*4 + i], acc);
  }
  const float s = acc * sigmoid_f(acc);
  const u16 h = f2bf(s);
  xh[idx] = h;
  xl[idx] = f2bf(s - bf2f(h));
}

// ------------------------------------------------- selective scan (per pair, 3-pass chunked)
__global__ __launch_bounds__(256)
void scan1_k(const float* __restrict__ dt, const u16* __restrict__ uh,
             const u16* __restrict__ ul, const float* __restrict__ BC,
             const float* __restrict__ A_log, float* __restrict__ Pb,
             float* __restrict__ Sb) {
  const int blk = blockIdx.x;              // bb*128 + c*8 + db
  const int db = blk & 7;
  const int c  = (blk >> 3) & (NCHUNK - 1);
  const int bb = blk >> 7;
  const int d  = db * 256 + threadIdx.x;
  float Av[DST];
  #pragma unroll
  for (int n = 0; n < DST; ++n) Av[n] = -__expf(A_log[n]);
  float P[DST], S[DST];
  #pragma unroll
  for (int n = 0; n < DST; ++n) { P[n] = 1.f; S[n] = 0.f; }
  for (int s = 0; s < CLEN; ++s) {
    const size_t row = (size_t)bb * SEQ + c * CLEN + s;
    const float dtv = dt[row * DI + d];
    const float uv  = bf2f(uh[row * DI + d]) + bf2f(ul[row * DI + d]);
    const float dtu = dtv * uv;
    const float* Brow = &BC[row * 32];
    #pragma unroll
    for (int n = 0; n < DST; ++n) {
      const float a = __expf(dtv * Av[n]);
      P[n] *= a;
      S[n] = fmaf(a, S[n], dtu * Brow[n]);
    }
  }
  const size_t off = ((size_t)(bb * NCHUNK + c) * DI + d) * DST;
  #pragma unroll
  for (int n = 0; n < DST; ++n) { Pb[off + n] = P[n]; Sb[off + n] = S[n]; }
}

__global__ __launch_bounds__(256)
void scan2_k(const float* __restrict__ Pb, const float* __restrict__ Sb,
             float* __restrict__ hs) {
  const int idx = blockIdx.x * 256 + threadIdx.x;   // bb*DI*DST + d*DST + n
  const int n = idx & (DST - 1);
  const int d = (idx >> 4) & (DI - 1);
  const int bb = idx >> 15;
  float h = 0.f;
  #pragma unroll
  for (int c = 0; c < NCHUNK; ++c) {
    const size_t off = ((size_t)(bb * NCHUNK + c) * DI + d) * DST + n;
    hs[off] = h;
    h = fmaf(Pb[off], h, Sb[off]);
  }
}

__global__ __launch_bounds__(256)
void scan3_k(const float* __restrict__ dt, const u16* __restrict__ uh,
             const u16* __restrict__ ul, const float* __restrict__ BC,
             const float* __restrict__ A_log, const float* __restrict__ hs,
             float* __restrict__ y) {
  const int blk = blockIdx.x;
  const int db = blk & 7;
  const int c  = (blk >> 3) & (NCHUNK - 1);
  const int bb = blk >> 7;
  const int d  = db * 256 + threadIdx.x;
  float Av[DST];
  #pragma unroll
  for (int n = 0; n < DST; ++n) Av[n] = -__expf(A_log[n]);
  float h[DST];
  const size_t hoff = ((size_t)(bb * NCHUNK + c) * DI + d) * DST;
  #pragma unroll
  for (int n = 0; n < DST; ++n) h[n] = hs[hoff + n];
  for (int s = 0; s < CLEN; ++s) {
    const size_t row = (size_t)bb * SEQ + c * CLEN + s;
    const float dtv = dt[row * DI + d];
    const float uv  = bf2f(uh[row * DI + d]) + bf2f(ul[row * DI + d]);
    const float dtu = dtv * uv;
    const float* Brow = &BC[row * 32];
    float yv = 0.f;
    #pragma unroll
    for (int n = 0; n < DST; ++n) {
      const float a = __expf(dtv * Av[n]);
      h[n] = fmaf(a, h[n], dtu * Brow[n]);
      yv = fmaf(h[n], Brow[DST + n], yv);
    }
    y[row * DI + d] = yv;
  }
}

// ------------------------------------------------- gate: g = (y + xc*D)*silu(z) -> bf16 (in z)
__global__ __launch_bounds__(256)
void elemwise_k(const float* __restrict__ y, const u16* __restrict__ xh,
                const u16* __restrict__ xl, const float* __restrict__ Dv,
                u16* __restrict__ z) {
  const int idx = blockIdx.x * 256 + threadIdx.x;
  const int d = idx & (DI - 1);
  const float zf = bf2f(z[idx]);
  const float xc = bf2f(xh[idx]) + bf2f(xl[idx]);
  float v = fmaf(xc, Dv[d], y[idx]);
  v *= zf * sigmoid_f(zf);
  z[idx] = f2bf(v);
}

// ================================================================ launch
extern "C" void kernel_launch(void* const* d_in, const int* in_sizes, int n_in,
                              void* d_out, int out_size, void* d_ws, size_t ws_size,
                              hipStream_t stream) {
  (void)in_sizes; (void)n_in;
  const float* x      = (const float*)d_in[0];
  const float* W_in   = (const float*)d_in[1];
  const float* conv_w = (const float*)d_in[2];
  const float* conv_b = (const float*)d_in[3];
  const float* W_x    = (const float*)d_in[4];
  const float* W_dt   = (const float*)d_in[5];
  const float* b_dt   = (const float*)d_in[6];
  const float* A_log  = (const float*)d_in[7];
  const float* Dvec   = (const float*)d_in[8];
  const float* W_out  = (const float*)d_in[9];
  float* out = (float*)d_out;

  // ---- workspace (~203 MB, fits known-safe >=206.5 MB) ----
  char* w = (char*)d_ws;
  size_t used = 0;
  auto alloc = [&](size_t bytes) {
    char* p = w + used; used += (bytes + 255) & ~(size_t)255; return p;
  };
  u16*   x_h     = (u16*)alloc((size_t)MROWS * DM * 2);     // 16.78 MB
  u16*   x_l     = (u16*)alloc((size_t)MROWS * DM * 2);
  u16*   WinT_h  = (u16*)alloc((size_t)(2*DI) * DM * 2);    //  8.39 MB
  u16*   WinT_l  = (u16*)alloc((size_t)(2*DI) * DM * 2);
  u16*   WcatT_h = (u16*)alloc((size_t)NCAT * DI * 2);      //  8.91 MB
  u16*   WcatT_l = (u16*)alloc((size_t)NCAT * DI * 2);
  u16*   WoutT   = (u16*)alloc((size_t)DM * DI * 2);        //  4.19 MB
  // per-pair activation buffers (PROWS = 4096 rows)
  float* xin  = (float*)alloc((size_t)PROWS * DI * 4);      // 33.55 MB (aliased as ybuf)
  u16*   z_bf = (u16*)  alloc((size_t)PROWS * DI * 2);      // 16.78 MB
  u16*   xc_h = (u16*)  alloc((size_t)PROWS * DI * 2);
  u16*   xc_l = (u16*)  alloc((size_t)PROWS * DI * 2);
  float* dtb  = (float*)alloc((size_t)PROWS * DI * 4);      // 33.55 MB
  float* BC   = (float*)alloc((size_t)PROWS * 32 * 4);      //  0.52 MB
  float* Pb   = (float*)alloc((size_t)2 * NCHUNK * DI * DST * 4);  // 4.19 MB
  float* Sb   = (float*)alloc((size_t)2 * NCHUNK * DI * DST * 4);
  float* hsb  = (float*)alloc((size_t)2 * NCHUNK * DI * DST * 4);
  const size_t NEED = used;
  float* ybuf = xin;   // xin dead after conv

  if (ws_size < NEED) {   // diagnostic fallback: clean absmax failure, not a crash
    hipMemsetAsync(d_out, 0, (size_t)out_size * 4, stream);
    return;
  }

  // weight prep (once)
  split_cast_k<<<(MROWS*DM/4 + 255)/256, 256, 0, stream>>>(x, x_h, x_l, MROWS*DM/4);
  transpose_cast_k<1><<<dim3((2*DI)/32, DM/32), dim3(32,8), 0, stream>>>(W_in, WinT_h, WinT_l, DM, 2*DI);
  transpose_cast_k<1><<<dim3(DI/32, DI/32), dim3(32,8), 0, stream>>>(W_dt, WcatT_h, WcatT_l, DI, DI);
  wcat_tail_k<<<(128*DI)/256, 256, 0, stream>>>(W_x, WcatT_h, WcatT_l);
  transpose_cast_k<0><<<dim3(DM/32, DI/32), dim3(32,8), 0, stream>>>(W_out, WoutT, nullptr, DI, DM);

  for (int p = 0; p < NBATCH/2; ++p) {
    const u16* xbh = x_h + (size_t)p * PROWS * DM;
    const u16* xbl = x_l + (size_t)p * PROWS * DM;

    // x_in = x @ W_in[:, :DI]  (split, f32 out)
    gemm_split_k<0><<<dim3(PROWS/128, DI/128), 256, 0, stream>>>(
        xbh, xbl, WinT_h, WinT_l, xin, nullptr, nullptr, DI, DM);
    // z = x @ W_in[:, DI:]  (plain bf16 — gate-only path)
    gemm_bf16_k<1><<<dim3(PROWS/128, DI/128), 256, 0, stream>>>(
        xbh, WinT_h + (size_t)DI*DM, z_bf, DI, DM);

    // causal depthwise conv + silu -> xc hi/lo
    conv_silu_k<<<PROWS*DI/256, 256, 0, stream>>>(xin, conv_w, conv_b, xc_h, xc_l);

    // dt = softplus(xc @ W_dt + b_dt); BC = xc @ W_x   (one fused split GEMM, N=2176)
    gemm_split_k<3><<<dim3(PROWS/128, NCAT/128), 256, 0, stream>>>(
        xc_h, xc_l, WcatT_h, WcatT_l, dtb, b_dt, BC, NCAT, DI);

    // selective scan (chunked linear recurrence), y f32 into ybuf (= xin region)
    scan1_k<<<2*NCHUNK*(DI/256), 256, 0, stream>>>(dtb, xc_h, xc_l, BC, A_log, Pb, Sb);
    scan2_k<<<2*DI*DST/256,      256, 0, stream>>>(Pb, Sb, hsb);
    scan3_k<<<2*NCHUNK*(DI/256), 256, 0, stream>>>(dtb, xc_h, xc_l, BC, A_log, hsb, ybuf);

    // gate + skip (bf16, in place into z)
    elemwise_k<<<PROWS*DI/256, 256, 0, stream>>>(ybuf, xc_h, xc_l, Dvec, z_bf);

    // out = gated @ W_out
    gemm_bf16_k<0><<<dim3(PROWS/128, DM/128), 256, 0, stream>>>(
        z_bf, WoutT, out + (size_t)p * PROWS * DM, DM, DI);
  }
}